// Round 5
// baseline (2682.107 us; speedup 1.0000x reference)
//
#include <hip/hip_runtime.h>
#include <cstdint>
#include <cstddef>

typedef __attribute__((ext_vector_type(8))) short bf16x8;   // 8 bf16 in 4 VGPRs
typedef __attribute__((ext_vector_type(4))) float f32x4;    // MFMA accumulator

static inline int cdiv(int a, int b) { return (a + b - 1) / b; }

__device__ inline unsigned short f2bf(float f) {
    union { float f; unsigned int u; } v; v.f = f;
    unsigned int u = v.u;
    return (unsigned short)((u + 0x7FFFu + ((u >> 16) & 1u)) >> 16);  // RNE
}
__device__ inline float bf2f(unsigned short b) {
    union { unsigned int u; float f; } v; v.u = ((unsigned int)b) << 16;
    return v.f;
}

// ---------------- CSR build (counting sort by dst) ----------------

__global__ void count_deg_kernel(const int* __restrict__ dst, int* __restrict__ deg, int nE) {
    int i = blockIdx.x * blockDim.x + threadIdx.x;
    if (i < nE) atomicAdd(&deg[dst[i]], 1);
}

__global__ void scan_kernel(const int* __restrict__ deg, int* __restrict__ rowptr,
                            int* __restrict__ cursor, int n) {
    __shared__ int sdata[256];
    __shared__ int carry_s;
    int tid = threadIdx.x;
    if (tid == 0) carry_s = 0;
    __syncthreads();
    for (int base = 0; base < n; base += 1024) {
        int vals[4];
        int local = 0;
#pragma unroll
        for (int i = 0; i < 4; ++i) {
            int idx = base + tid * 4 + i;
            vals[i] = (idx < n) ? deg[idx] : 0;
            local += vals[i];
        }
        sdata[tid] = local;
        __syncthreads();
        for (int off = 1; off < 256; off <<= 1) {
            int t = (tid >= off) ? sdata[tid - off] : 0;
            __syncthreads();
            sdata[tid] += t;
            __syncthreads();
        }
        int excl = sdata[tid] - local;
        int c0 = carry_s;
        int run = c0 + excl;
#pragma unroll
        for (int i = 0; i < 4; ++i) {
            int idx = base + tid * 4 + i;
            if (idx < n) { rowptr[idx] = run; cursor[idx] = run; }
            run += vals[i];
        }
        __syncthreads();
        if (tid == 255) carry_s = c0 + sdata[255];
        __syncthreads();
    }
    if (tid == 0) rowptr[n] = carry_s;
}

// ---------------- weight transpose + bf16: Wt[n][k] = bf16(W[k][n]) ----------------

__global__ void transpose_w(const float* __restrict__ W, unsigned short* __restrict__ Wt,
                            int K, int N, int Npad) {
    int i = blockIdx.x * blockDim.x + threadIdx.x;
    if (i >= Npad * K) return;
    int n = i / K, k = i - n * K;
    float v = (n < N) ? W[(size_t)k * N + n] : 0.f;
    Wt[i] = f2bf(v);
}

// ---------------- bf16 MFMA GEMM body (m97 structure): C[M,N] = A[M,K] @ Bt[N,K]^T ----------------

template <int BN, bool AF32>
__device__ void gemm_body(const void* __restrict__ Av,
                          const unsigned short* __restrict__ Bt,
                          unsigned short* __restrict__ C,
                          int M, int K, int N, int bx, int by) {
    constexpr int BM = 128, BK = 64;
    __shared__ unsigned short As[BM * BK];
    __shared__ unsigned short Bs[BN * BK];
    const int tid = threadIdx.x;
    const int lane = tid & 63, wid = tid >> 6;
    const int m0 = bx * BM, n0 = by * BN;

    constexpr int WN = (BN == 128) ? 2 : 1;
    constexpr int WTM = (BN == 128) ? 64 : 32;
    constexpr int FM = WTM / 16, FN = 4;
    const int wm = (wid / WN) * WTM;
    const int wn = (wid % WN) * 64;
    const int g = lane >> 4, r16 = lane & 15;

    const unsigned short* A16 = (const unsigned short*)Av;
    const float* A32 = (const float*)Av;

    f32x4 acc[FM][FN] = {};

    for (int k0 = 0; k0 < K; k0 += BK) {
        if constexpr (AF32) {
#pragma unroll
            for (int it = 0; it < 4; ++it) {
                int c = it * 256 + tid;
                int r = c >> 3, kc = c & 7;
                int gm = m0 + r;
                bf16x8 val;
                if (gm < M) {
                    const float* p = A32 + (size_t)gm * K + k0 + kc * 8;
                    float4 v0 = *reinterpret_cast<const float4*>(p);
                    float4 v1 = *reinterpret_cast<const float4*>(p + 4);
                    val[0] = (short)f2bf(v0.x); val[1] = (short)f2bf(v0.y);
                    val[2] = (short)f2bf(v0.z); val[3] = (short)f2bf(v0.w);
                    val[4] = (short)f2bf(v1.x); val[5] = (short)f2bf(v1.y);
                    val[6] = (short)f2bf(v1.z); val[7] = (short)f2bf(v1.w);
                } else {
#pragma unroll
                    for (int j = 0; j < 8; ++j) val[j] = 0;
                }
                *reinterpret_cast<bf16x8*>(&As[r * BK + kc * 8]) = val;
            }
        } else {
#pragma unroll
            for (int c = 0; c < 4; ++c) {
                int base = wid * 32 + c * 8;
                int row = base + (lane >> 3), kc = lane & 7;
                const unsigned short* gp = A16 + (size_t)(m0 + row) * K + k0 + kc * 8;
                __builtin_amdgcn_global_load_lds(
                    (const __attribute__((address_space(1))) void*)gp,
                    (__attribute__((address_space(3))) void*)&As[base * BK], 16, 0, 0);
            }
        }
        {
            constexpr int BCALLS = (BN * BK) / (512 * 4);
#pragma unroll
            for (int c = 0; c < BCALLS; ++c) {
                int base = wid * (BN / 4) + c * 8;
                int row = base + (lane >> 3), kc = lane & 7;
                const unsigned short* gp = Bt + (size_t)(n0 + row) * K + k0 + kc * 8;
                __builtin_amdgcn_global_load_lds(
                    (const __attribute__((address_space(1))) void*)gp,
                    (__attribute__((address_space(3))) void*)&Bs[base * BK], 16, 0, 0);
            }
        }
        __syncthreads();
#pragma unroll
        for (int ks = 0; ks < 2; ++ks) {
            bf16x8 af[FM], bfr[FN];
#pragma unroll
            for (int i = 0; i < FM; ++i)
                af[i] = *reinterpret_cast<const bf16x8*>(&As[(wm + i * 16 + r16) * BK + ks * 32 + g * 8]);
#pragma unroll
            for (int j = 0; j < FN; ++j)
                bfr[j] = *reinterpret_cast<const bf16x8*>(&Bs[(wn + j * 16 + r16) * BK + ks * 32 + g * 8]);
#pragma unroll
            for (int i = 0; i < FM; ++i)
#pragma unroll
                for (int j = 0; j < FN; ++j)
                    acc[i][j] = __builtin_amdgcn_mfma_f32_16x16x32_bf16(af[i], bfr[j], acc[i][j], 0, 0, 0);
        }
        __syncthreads();
    }
#pragma unroll
    for (int i = 0; i < FM; ++i) {
        int gmBase = m0 + wm + i * 16 + g * 4;
#pragma unroll
        for (int j = 0; j < FN; ++j) {
            int gn = n0 + wn + j * 16 + r16;
            if (gn < N) {
#pragma unroll
                for (int r = 0; r < 4; ++r) {
                    int gm = gmBase + r;
                    if (gm < M) C[(size_t)gm * N + gn] = f2bf(acc[i][j][r]);
                }
            }
        }
    }
}

template <int BN, bool AF32>
__global__ __launch_bounds__(256) void gemm_mfma(const void* __restrict__ Av,
                                                 const unsigned short* __restrict__ Bt,
                                                 unsigned short* __restrict__ C,
                                                 int M, int K, int N) {
    gemm_body<BN, AF32>(Av, Bt, C, M, K, N, blockIdx.x, blockIdx.y);
}

// ---------------- fused: GEMM layer-1 (f32 A) || edge scatter ----------------
// every f-th block is a gemm block; others do the scatter.

template <int BN>
__global__ __launch_bounds__(256) void fused_gemm_scatter(
        const void* __restrict__ Av, const unsigned short* __restrict__ Bt,
        unsigned short* __restrict__ C, int M, int K, int N, int nGx, int nG, int f,
        const int* __restrict__ src, const int* __restrict__ dst,
        const float* __restrict__ w, int* __restrict__ cursor,
        int2* __restrict__ ep, int nE) {
    int bid = blockIdx.x;
    bool isG = ((bid % f) == 0) && ((bid / f) < nG);
    if (isG) {
        int gid = bid / f;
        gemm_body<BN, true>(Av, Bt, C, M, K, N, gid % nGx, gid / nGx);
    } else {
        int gBefore = min(bid / f + 1, nG);
        int i = (bid - gBefore) * 256 + threadIdx.x;
        if (i < nE) {
            int d = dst[i];
            int pos = atomicAdd(&cursor[d], 1);
            ep[pos] = make_int2(src[i], __float_as_int(w[i]));
        }
    }
}

// ---------------- CSR aggregation (bf16 supp -> bf16 h), fused bias+ReLU ----------------
// one wave per node; FO/8 lanes per row (bf16x8 loads), 64/(FO/8) edges in parallel

template <int FO>
__global__ __launch_bounds__(256) void agg_kernel(const unsigned short* __restrict__ supp,
                                                  const int2* __restrict__ ep,
                                                  const int* __restrict__ rowptr,
                                                  const float* __restrict__ bias,
                                                  unsigned short* __restrict__ out, int n_nodes) {
    constexpr int LPR = FO / 8;     // lanes per row: 32/16/8
    constexpr int EPS = 64 / LPR;   // parallel edges per step: 2/4/8
    int node = (int)((blockIdx.x * blockDim.x + threadIdx.x) >> 6);
    int lane = threadIdx.x & 63;
    if (node >= n_nodes) return;
    int beg = __builtin_amdgcn_readfirstlane(rowptr[node]);
    int end = __builtin_amdgcn_readfirstlane(rowptr[node + 1]);
    const int lr = lane & (LPR - 1);
    const int half = lane / LPR;    // which of the EPS edges this lane serves
    float a[8] = {};
    int e = beg;
    for (; e + 8 <= end; e += 8) {
#pragma unroll
        for (int u = 0; u < 8 / EPS; ++u) {
            int2 me = ep[e + u * EPS + half];
            bf16x8 v = *reinterpret_cast<const bf16x8*>(supp + (size_t)me.x * FO + lr * 8);
            float wv = __int_as_float(me.y);
#pragma unroll
            for (int j = 0; j < 8; ++j) a[j] += wv * bf2f((unsigned short)v[j]);
        }
    }
    for (; e < end; ++e) {
        int2 me = ep[e];
        bf16x8 v = *reinterpret_cast<const bf16x8*>(supp + (size_t)me.x * FO + lr * 8);
        float wv = (half == 0) ? __int_as_float(me.y) : 0.f;
#pragma unroll
        for (int j = 0; j < 8; ++j) a[j] += wv * bf2f((unsigned short)v[j]);
    }
    // reduce across the EPS edge-groups
#pragma unroll
    for (int off = LPR; off < 64; off <<= 1)
#pragma unroll
        for (int j = 0; j < 8; ++j) a[j] += __shfl_xor(a[j], off);
    if (lane < LPR) {
        float4 b0 = *reinterpret_cast<const float4*>(bias + lane * 8);
        float4 b1 = *reinterpret_cast<const float4*>(bias + lane * 8 + 4);
        float bb[8] = {b0.x, b0.y, b0.z, b0.w, b1.x, b1.y, b1.z, b1.w};
        bf16x8 o;
#pragma unroll
        for (int j = 0; j < 8; ++j) o[j] = (short)f2bf(fmaxf(a[j] + bb[j], 0.f));
        *reinterpret_cast<bf16x8*>(out + (size_t)node * FO + lane * 8) = o;
    }
}

// ---------------- final layer: padded-64 supp, agg + bias + log_softmax (f32 out) ----------------
// supp stride 64; cols 40..63 are exact zeros. 8 lanes/row, 8 edges/step.

__global__ __launch_bounds__(256) void agg_lsm_kernel(const unsigned short* __restrict__ supp,
                                                      const int2* __restrict__ ep,
                                                      const int* __restrict__ rowptr,
                                                      const float* __restrict__ bias,
                                                      float* __restrict__ out, int n_nodes) {
    int node = (int)((blockIdx.x * blockDim.x + threadIdx.x) >> 6);
    int lane = threadIdx.x & 63;
    if (node >= n_nodes) return;
    int beg = __builtin_amdgcn_readfirstlane(rowptr[node]);
    int end = __builtin_amdgcn_readfirstlane(rowptr[node + 1]);
    const int lr = lane & 7;
    const int half = lane >> 3;
    float a[8] = {};
    int e = beg;
    for (; e + 8 <= end; e += 8) {
        int2 me = ep[e + half];
        bf16x8 v = *reinterpret_cast<const bf16x8*>(supp + (size_t)me.x * 64 + lr * 8);
        float wv = __int_as_float(me.y);
#pragma unroll
        for (int j = 0; j < 8; ++j) a[j] += wv * bf2f((unsigned short)v[j]);
    }
    for (; e < end; ++e) {
        int2 me = ep[e];
        bf16x8 v = *reinterpret_cast<const bf16x8*>(supp + (size_t)me.x * 64 + lr * 8);
        float wv = (half == 0) ? __int_as_float(me.y) : 0.f;
#pragma unroll
        for (int j = 0; j < 8; ++j) a[j] += wv * bf2f((unsigned short)v[j]);
    }
#pragma unroll
    for (int off = 8; off < 64; off <<= 1)
#pragma unroll
        for (int j = 0; j < 8; ++j) a[j] += __shfl_xor(a[j], off);
    // lanes 0..7 hold cols lane*8 .. lane*8+7
    float vj[8];
#pragma unroll
    for (int j = 0; j < 8; ++j) {
        int col = lane * 8 + j;  // valid only for lane<8
        float bv = (lane < 8 && col < 40) ? bias[col] : 0.f;
        vj[j] = (col < 40) ? (a[j] + bv) : -1e30f;
    }
    float m = vj[0];
#pragma unroll
    for (int j = 1; j < 8; ++j) m = fmaxf(m, vj[j]);
#pragma unroll
    for (int off = 1; off < 8; off <<= 1) m = fmaxf(m, __shfl_xor(m, off));
    float s = 0.f;
#pragma unroll
    for (int j = 0; j < 8; ++j) s += expf(vj[j] - m);
#pragma unroll
    for (int off = 1; off < 8; off <<= 1) s += __shfl_xor(s, off);
    float ls = m + logf(s);
    if (lane < 5) {
        float4 o0, o1;
        o0.x = vj[0] - ls; o0.y = vj[1] - ls; o0.z = vj[2] - ls; o0.w = vj[3] - ls;
        o1.x = vj[4] - ls; o1.y = vj[5] - ls; o1.z = vj[6] - ls; o1.w = vj[7] - ls;
        float* op = out + (size_t)node * 40 + lane * 8;
        *reinterpret_cast<float4*>(op) = o0;
        *reinterpret_cast<float4*>(op + 4) = o1;
    }
}

// ---------------- launch ----------------

extern "C" void kernel_launch(void* const* d_in, const int* in_sizes, int n_in,
                              void* d_out, int out_size, void* d_ws, size_t ws_size,
                              hipStream_t stream) {
    const float* x    = (const float*)d_in[0];
    const int*   esrc = (const int*)d_in[1];
    const int*   edst = (const int*)d_in[2];
    const float* ew   = (const float*)d_in[3];
    const float* W[9];
    const float* b[9];
    for (int i = 0; i < 9; ++i) {
        W[i] = (const float*)d_in[4 + 2 * i];
        b[i] = (const float*)d_in[5 + 2 * i];
    }
    const int nN = in_sizes[0] / 512;  // 100000
    const int nE = in_sizes[1];        // 3200000

    const int dims[10] = {512, 256, 256, 256, 256, 256, 128, 128, 64, 40};

    // ---- workspace layout (GEMM A-tile tail blocks read up to ~48KB past h/supp;
    // keep live regions after them) ----
    char* ws = (char*)d_ws;
    unsigned short* h    = (unsigned short*)ws;                       // nN*256 bf16
    unsigned short* supp = (unsigned short*)(ws + (size_t)nN * 256 * 2);
    char* p = ws + (size_t)nN * 256 * 2 * 2;
    unsigned short* Wt = (unsigned short*)p; p += (1 << 21);          // padded bf16 W^T
    int* deg    = (int*)p; p += ((size_t)nN + 64) * 4;
    int* rowptr = (int*)p; p += ((size_t)nN + 64) * 4;
    int* cursor = (int*)p; p += ((size_t)nN + 64) * 4;
    int2* ep    = (int2*)p; p += (size_t)nE * 8;

    // ---- transpose+convert weights: Wt[i] is [fo_pad][fi] row-major ----
    size_t woff[9];
    {
        size_t off = 0;
        for (int i = 0; i < 9; ++i) {
            woff[i] = off;
            int fi = dims[i], fo = dims[i + 1];
            int fop = cdiv(fo, 64) * 64;
            int sz = fop * fi;
            transpose_w<<<cdiv(sz, 256), 256, 0, stream>>>(W[i], Wt + off, fi, fo, fop);
            off += (size_t)sz;
        }
    }

    // ---- CSR count + scan ----
    hipMemsetAsync(deg, 0, (size_t)nN * 4, stream);
    count_deg_kernel<<<cdiv(nE, 256), 256, 0, stream>>>(edst, deg, nE);
    scan_kernel<<<1, 256, 0, stream>>>(deg, rowptr, cursor, nN);

    const int aggBlocks = cdiv(nN, 4);  // 4 waves/block, 1 node/wave

    // ---- fused: GEMM layer-1 || scatter ----
    {
        int nGx = cdiv(nN, 128), nGy = cdiv(dims[1], 128);
        int nG = nGx * nGy;
        int nS = cdiv(nE, 256);
        int T = nG + nS;
        int f = T / nG; if (f < 1) f = 1;
        fused_gemm_scatter<128><<<T, 256, 0, stream>>>(
            (const void*)x, Wt + woff[0], supp, nN, dims[0], dims[1], nGx, nG, f,
            esrc, edst, ew, cursor, ep, nE);
    }
    agg_kernel<256><<<aggBlocks, 256, 0, stream>>>(supp, ep, rowptr, b[0], h, nN);

    const void* A = (const void*)h;
    for (int L = 1; L < 9; ++L) {
        int fi = dims[L], fo = dims[L + 1];
        if (L == 8) {
            dim3 g(cdiv(nN, 128), 1);
            gemm_mfma<64, false><<<g, 256, 0, stream>>>(A, Wt + woff[L], supp, nN, fi, 64);
            agg_lsm_kernel<<<aggBlocks, 256, 0, stream>>>(supp, ep, rowptr, b[8], (float*)d_out, nN);
            break;
        }
        int BN = (fo >= 128) ? 128 : 64;
        dim3 g(cdiv(nN, 128), cdiv(fo, BN));
        if (BN == 128)
            gemm_mfma<128, false><<<g, 256, 0, stream>>>(A, Wt + woff[L], supp, nN, fi, fo);
        else
            gemm_mfma<64, false><<<g, 256, 0, stream>>>(A, Wt + woff[L], supp, nN, fi, fo);
        if (fo == 256)
            agg_kernel<256><<<aggBlocks, 256, 0, stream>>>(supp, ep, rowptr, b[L], h, nN);
        else if (fo == 128)
            agg_kernel<128><<<aggBlocks, 256, 0, stream>>>(supp, ep, rowptr, b[L], h, nN);
        else
            agg_kernel<64><<<aggBlocks, 256, 0, stream>>>(supp, ep, rowptr, b[L], h, nN);
        A = (const void*)h;
    }
}

// Round 6
// 2102.736 us; speedup vs baseline: 1.2755x; 1.2755x over previous
//
#include <hip/hip_runtime.h>
#include <cstdint>
#include <cstddef>

typedef __attribute__((ext_vector_type(8))) short bf16x8;   // 8 bf16 in 4 VGPRs
typedef __attribute__((ext_vector_type(4))) float f32x4;    // MFMA accumulator

static inline int cdiv(int a, int b) { return (a + b - 1) / b; }

__device__ inline unsigned short f2bf(float f) {
    union { float f; unsigned int u; } v; v.f = f;
    unsigned int u = v.u;
    return (unsigned short)((u + 0x7FFFu + ((u >> 16) & 1u)) >> 16);  // RNE
}
__device__ inline float bf2f(unsigned short b) {
    union { unsigned int u; float f; } v; v.u = ((unsigned int)b) << 16;
    return v.f;
}

// ---------------- prep: all weight transposes (f32->bf16, [fo_pad][fi]) + zero deg/bucketCursor ----------------

struct TW {
    const float* W[9];
    int K[9];      // fi
    int N[9];      // fo
    int base[10];  // cumulative output offsets (elements)
    int nN;
};

__global__ __launch_bounds__(256) void prep_kernel(TW tw, unsigned short* __restrict__ Wt,
                                                   int* __restrict__ deg,
                                                   int* __restrict__ bucketCursor, int total) {
    int t = blockIdx.x * 256 + threadIdx.x;
    if (t < tw.nN) deg[t] = 0;
    if (t < 8) bucketCursor[t] = 0;
    if (t >= total) return;
    int l = 0;
#pragma unroll
    for (int i = 1; i <= 8; ++i)
        if (t >= tw.base[i]) l = i;
    int loc = t - tw.base[l];
    int K = tw.K[l], N = tw.N[l];
    int n = loc / K, k = loc - n * K;
    float v = (n < N) ? tw.W[l][(size_t)k * N + n] : 0.f;
    Wt[t] = f2bf(v);
}

// ---------------- phase A: degree count + bucket partition (coalesced staging) ----------------

__global__ __launch_bounds__(256) void partition_kernel(
        const int* __restrict__ src, const int* __restrict__ dst,
        const float* __restrict__ w, int* __restrict__ deg,
        int* __restrict__ bucketCursor, int4* __restrict__ staging,
        int bucketCap, int nE, int nN) {
    __shared__ int lcount[8];
    __shared__ int lbase[8];
    int tid = threadIdx.x;
    int i = blockIdx.x * 256 + tid;
    if (tid < 8) lcount[tid] = 0;
    __syncthreads();
    int b = 0, d = 0, s = 0, lslot = 0;
    float wv = 0.f;
    bool act = (i < nE);
    if (act) {
        d = dst[i]; s = src[i]; wv = w[i];
        atomicAdd(&deg[d], 1);
        b = (d * 8) / nN;                       // 8 dst-range buckets
        lslot = atomicAdd(&lcount[b], 1);
    }
    __syncthreads();
    if (tid < 8) lbase[tid] = lcount[tid] ? atomicAdd(&bucketCursor[tid], lcount[tid]) : 0;
    __syncthreads();
    if (act) {
        int pos = lbase[b] + lslot;
        staging[(size_t)b * bucketCap + pos] = make_int4(d, s, __float_as_int(wv), 0);
    }
}

// ---------------- hierarchical exclusive scan of deg -> rowptr, cursor ----------------

__global__ __launch_bounds__(256) void scan_part(const int* __restrict__ deg,
                                                 int* __restrict__ partials, int n) {
    __shared__ int sdata[256];
    int tid = threadIdx.x;
    int base = blockIdx.x * 1024;
    int local = 0;
#pragma unroll
    for (int i = 0; i < 4; ++i) {
        int idx = base + tid * 4 + i;
        local += (idx < n) ? deg[idx] : 0;
    }
    sdata[tid] = local;
    __syncthreads();
    for (int off = 128; off; off >>= 1) {
        if (tid < off) sdata[tid] += sdata[tid + off];
        __syncthreads();
    }
    if (tid == 0) partials[blockIdx.x] = sdata[0];
}

__global__ void scan_mid(int* __restrict__ partials, int* __restrict__ rowptr, int nb, int nN) {
    __shared__ int s[128];
    int tid = threadIdx.x;
    int v = (tid < nb) ? partials[tid] : 0;
    s[tid] = v;
    __syncthreads();
    for (int off = 1; off < 128; off <<= 1) {
        int t = (tid >= off) ? s[tid - off] : 0;
        __syncthreads();
        s[tid] += t;
        __syncthreads();
    }
    if (tid < nb) partials[tid] = s[tid] - v;  // exclusive
    if (tid == nb - 1) rowptr[nN] = s[tid];
}

__global__ __launch_bounds__(256) void scan_final(const int* __restrict__ deg,
                                                  const int* __restrict__ partials,
                                                  int* __restrict__ rowptr,
                                                  int* __restrict__ cursor, int n) {
    __shared__ int sdata[256];
    int tid = threadIdx.x;
    int base = blockIdx.x * 1024;
    int vals[4];
    int local = 0;
#pragma unroll
    for (int i = 0; i < 4; ++i) {
        int idx = base + tid * 4 + i;
        vals[i] = (idx < n) ? deg[idx] : 0;
        local += vals[i];
    }
    sdata[tid] = local;
    __syncthreads();
    for (int off = 1; off < 256; off <<= 1) {
        int t = (tid >= off) ? sdata[tid - off] : 0;
        __syncthreads();
        sdata[tid] += t;
        __syncthreads();
    }
    int run = sdata[tid] - local + partials[blockIdx.x];
#pragma unroll
    for (int i = 0; i < 4; ++i) {
        int idx = base + tid * 4 + i;
        if (idx < n) { rowptr[idx] = run; cursor[idx] = run; }
        run += vals[i];
    }
}

// ---------------- phase B: per-bucket scatter (bucket b on blocks bid%8==b -> XCD-local ep window) ----------------

__global__ __launch_bounds__(256) void scatter_b(const int4* __restrict__ staging,
                                                 const int* __restrict__ bucketCnt,
                                                 int bucketCap, int* __restrict__ cursor,
                                                 int2* __restrict__ ep, int blocksPerBucket) {
    int bucket = blockIdx.x & 7;
    int chunk = blockIdx.x >> 3;
    int cnt = bucketCnt[bucket];
    const int4* st = staging + (size_t)bucket * bucketCap;
    for (int i = chunk * 256 + threadIdx.x; i < cnt; i += blocksPerBucket * 256) {
        int4 r = st[i];
        int pos = atomicAdd(&cursor[r.x], 1);
        ep[pos] = make_int2(r.y, r.z);
    }
}

// ---------------- bf16 MFMA GEMM (m97 structure): C[M,N] = A[M,K] @ Bt[N,K]^T ----------------

template <int BN, bool AF32>
__global__ __launch_bounds__(256) void gemm_mfma(const void* __restrict__ Av,
                                                 const unsigned short* __restrict__ Bt,
                                                 unsigned short* __restrict__ C,
                                                 int M, int K, int N) {
    constexpr int BM = 128, BK = 64;
    __shared__ unsigned short As[BM * BK];
    __shared__ unsigned short Bs[BN * BK];
    const int tid = threadIdx.x;
    const int lane = tid & 63, wid = tid >> 6;
    const int m0 = blockIdx.x * BM, n0 = blockIdx.y * BN;

    constexpr int WN = (BN == 128) ? 2 : 1;
    constexpr int WTM = (BN == 128) ? 64 : 32;
    constexpr int FM = WTM / 16, FN = 4;
    const int wm = (wid / WN) * WTM;
    const int wn = (wid % WN) * 64;
    const int g = lane >> 4, r16 = lane & 15;

    const unsigned short* A16 = (const unsigned short*)Av;
    const float* A32 = (const float*)Av;

    f32x4 acc[FM][FN] = {};

    for (int k0 = 0; k0 < K; k0 += BK) {
        if constexpr (AF32) {
#pragma unroll
            for (int it = 0; it < 4; ++it) {
                int c = it * 256 + tid;
                int r = c >> 3, kc = c & 7;
                int gm = m0 + r;
                bf16x8 val;
                if (gm < M) {
                    const float* p = A32 + (size_t)gm * K + k0 + kc * 8;
                    float4 v0 = *reinterpret_cast<const float4*>(p);
                    float4 v1 = *reinterpret_cast<const float4*>(p + 4);
                    val[0] = (short)f2bf(v0.x); val[1] = (short)f2bf(v0.y);
                    val[2] = (short)f2bf(v0.z); val[3] = (short)f2bf(v0.w);
                    val[4] = (short)f2bf(v1.x); val[5] = (short)f2bf(v1.y);
                    val[6] = (short)f2bf(v1.z); val[7] = (short)f2bf(v1.w);
                } else {
#pragma unroll
                    for (int j = 0; j < 8; ++j) val[j] = 0;
                }
                *reinterpret_cast<bf16x8*>(&As[r * BK + kc * 8]) = val;
            }
        } else {
#pragma unroll
            for (int c = 0; c < 4; ++c) {
                int base = wid * 32 + c * 8;
                int row = base + (lane >> 3), kc = lane & 7;
                const unsigned short* gp = A16 + (size_t)(m0 + row) * K + k0 + kc * 8;
                __builtin_amdgcn_global_load_lds(
                    (const __attribute__((address_space(1))) void*)gp,
                    (__attribute__((address_space(3))) void*)&As[base * BK], 16, 0, 0);
            }
        }
        {
            constexpr int BCALLS = (BN * BK) / (512 * 4);
#pragma unroll
            for (int c = 0; c < BCALLS; ++c) {
                int base = wid * (BN / 4) + c * 8;
                int row = base + (lane >> 3), kc = lane & 7;
                const unsigned short* gp = Bt + (size_t)(n0 + row) * K + k0 + kc * 8;
                __builtin_amdgcn_global_load_lds(
                    (const __attribute__((address_space(1))) void*)gp,
                    (__attribute__((address_space(3))) void*)&Bs[base * BK], 16, 0, 0);
            }
        }
        __syncthreads();
#pragma unroll
        for (int ks = 0; ks < 2; ++ks) {
            bf16x8 af[FM], bfr[FN];
#pragma unroll
            for (int i = 0; i < FM; ++i)
                af[i] = *reinterpret_cast<const bf16x8*>(&As[(wm + i * 16 + r16) * BK + ks * 32 + g * 8]);
#pragma unroll
            for (int j = 0; j < FN; ++j)
                bfr[j] = *reinterpret_cast<const bf16x8*>(&Bs[(wn + j * 16 + r16) * BK + ks * 32 + g * 8]);
#pragma unroll
            for (int i = 0; i < FM; ++i)
#pragma unroll
                for (int j = 0; j < FN; ++j)
                    acc[i][j] = __builtin_amdgcn_mfma_f32_16x16x32_bf16(af[i], bfr[j], acc[i][j], 0, 0, 0);
        }
        __syncthreads();
    }
#pragma unroll
    for (int i = 0; i < FM; ++i) {
        int gmBase = m0 + wm + i * 16 + g * 4;
#pragma unroll
        for (int j = 0; j < FN; ++j) {
            int gn = n0 + wn + j * 16 + r16;
            if (gn < N) {
#pragma unroll
                for (int r = 0; r < 4; ++r) {
                    int gm = gmBase + r;
                    if (gm < M) C[(size_t)gm * N + gn] = f2bf(acc[i][j][r]);
                }
            }
        }
    }
}

// ---------------- CSR aggregation (bf16 supp -> bf16 h), fused bias+ReLU ----------------
// one wave per node; FO/8 lanes per row (bf16x8 loads), 64/(FO/8) edges in parallel,
// 16-edge software pipeline

template <int FO>
__global__ __launch_bounds__(256) void agg_kernel(const unsigned short* __restrict__ supp,
                                                  const int2* __restrict__ ep,
                                                  const int* __restrict__ rowptr,
                                                  const float* __restrict__ bias,
                                                  unsigned short* __restrict__ out, int n_nodes) {
    constexpr int LPR = FO / 8;     // lanes per row: 32/16/8
    constexpr int EPS = 64 / LPR;   // parallel edges per step: 2/4/8
    constexpr int G16 = 16 / EPS;   // groups in 16-edge step
    constexpr int G8 = 8 / EPS;     // groups in 8-edge step
    int node = (int)((blockIdx.x * blockDim.x + threadIdx.x) >> 6);
    int lane = threadIdx.x & 63;
    if (node >= n_nodes) return;
    int beg = __builtin_amdgcn_readfirstlane(rowptr[node]);
    int end = __builtin_amdgcn_readfirstlane(rowptr[node + 1]);
    const int lr = lane & (LPR - 1);
    const int half = lane / LPR;
    float a[8] = {};
    int e = beg;
    for (; e + 16 <= end; e += 16) {
        int2 me[G16];
        bf16x8 v[G16];
#pragma unroll
        for (int u = 0; u < G16; ++u) me[u] = ep[e + u * EPS + half];
#pragma unroll
        for (int u = 0; u < G16; ++u)
            v[u] = *reinterpret_cast<const bf16x8*>(supp + (size_t)me[u].x * FO + lr * 8);
#pragma unroll
        for (int u = 0; u < G16; ++u) {
            float wv = __int_as_float(me[u].y);
#pragma unroll
            for (int j = 0; j < 8; ++j) a[j] += wv * bf2f((unsigned short)v[u][j]);
        }
    }
    for (; e + 8 <= end; e += 8) {
        int2 me[G8];
        bf16x8 v[G8];
#pragma unroll
        for (int u = 0; u < G8; ++u) me[u] = ep[e + u * EPS + half];
#pragma unroll
        for (int u = 0; u < G8; ++u)
            v[u] = *reinterpret_cast<const bf16x8*>(supp + (size_t)me[u].x * FO + lr * 8);
#pragma unroll
        for (int u = 0; u < G8; ++u) {
            float wv = __int_as_float(me[u].y);
#pragma unroll
            for (int j = 0; j < 8; ++j) a[j] += wv * bf2f((unsigned short)v[u][j]);
        }
    }
    for (; e < end; ++e) {
        int2 me = ep[e];
        bf16x8 v = *reinterpret_cast<const bf16x8*>(supp + (size_t)me.x * FO + lr * 8);
        float wv = (half == 0) ? __int_as_float(me.y) : 0.f;
#pragma unroll
        for (int j = 0; j < 8; ++j) a[j] += wv * bf2f((unsigned short)v[j]);
    }
    // reduce across the EPS edge-groups
#pragma unroll
    for (int off = LPR; off < 64; off <<= 1)
#pragma unroll
        for (int j = 0; j < 8; ++j) a[j] += __shfl_xor(a[j], off);
    if (lane < LPR) {
        float4 b0 = *reinterpret_cast<const float4*>(bias + lane * 8);
        float4 b1 = *reinterpret_cast<const float4*>(bias + lane * 8 + 4);
        float bb[8] = {b0.x, b0.y, b0.z, b0.w, b1.x, b1.y, b1.z, b1.w};
        bf16x8 o;
#pragma unroll
        for (int j = 0; j < 8; ++j) o[j] = (short)f2bf(fmaxf(a[j] + bb[j], 0.f));
        *reinterpret_cast<bf16x8*>(out + (size_t)node * FO + lane * 8) = o;
    }
}

// ---------------- final layer: padded-64 supp, agg + bias + log_softmax (f32 out) ----------------
// supp stride 64; cols 40..63 exact zeros. 8 lanes/row, 8 edges/step, 16-edge pipeline.

__global__ __launch_bounds__(256) void agg_lsm_kernel(const unsigned short* __restrict__ supp,
                                                      const int2* __restrict__ ep,
                                                      const int* __restrict__ rowptr,
                                                      const float* __restrict__ bias,
                                                      float* __restrict__ out, int n_nodes) {
    int node = (int)((blockIdx.x * blockDim.x + threadIdx.x) >> 6);
    int lane = threadIdx.x & 63;
    if (node >= n_nodes) return;
    int beg = __builtin_amdgcn_readfirstlane(rowptr[node]);
    int end = __builtin_amdgcn_readfirstlane(rowptr[node + 1]);
    const int lr = lane & 7;
    const int half = lane >> 3;
    float a[8] = {};
    int e = beg;
    for (; e + 16 <= end; e += 16) {
        int2 me0 = ep[e + half];
        int2 me1 = ep[e + 8 + half];
        bf16x8 v0 = *reinterpret_cast<const bf16x8*>(supp + (size_t)me0.x * 64 + lr * 8);
        bf16x8 v1 = *reinterpret_cast<const bf16x8*>(supp + (size_t)me1.x * 64 + lr * 8);
        float w0 = __int_as_float(me0.y), w1 = __int_as_float(me1.y);
#pragma unroll
        for (int j = 0; j < 8; ++j)
            a[j] += w0 * bf2f((unsigned short)v0[j]) + w1 * bf2f((unsigned short)v1[j]);
    }
    for (; e + 8 <= end; e += 8) {
        int2 me = ep[e + half];
        bf16x8 v = *reinterpret_cast<const bf16x8*>(supp + (size_t)me.x * 64 + lr * 8);
        float wv = __int_as_float(me.y);
#pragma unroll
        for (int j = 0; j < 8; ++j) a[j] += wv * bf2f((unsigned short)v[j]);
    }
    for (; e < end; ++e) {
        int2 me = ep[e];
        bf16x8 v = *reinterpret_cast<const bf16x8*>(supp + (size_t)me.x * 64 + lr * 8);
        float wv = (half == 0) ? __int_as_float(me.y) : 0.f;
#pragma unroll
        for (int j = 0; j < 8; ++j) a[j] += wv * bf2f((unsigned short)v[j]);
    }
#pragma unroll
    for (int off = 8; off < 64; off <<= 1)
#pragma unroll
        for (int j = 0; j < 8; ++j) a[j] += __shfl_xor(a[j], off);
    // lanes 0..7 hold cols lane*8 .. lane*8+7
    float vj[8];
#pragma unroll
    for (int j = 0; j < 8; ++j) {
        int col = lane * 8 + j;
        float bv = (lane < 8 && col < 40) ? bias[col] : 0.f;
        vj[j] = (col < 40) ? (a[j] + bv) : -1e30f;
    }
    float m = vj[0];
#pragma unroll
    for (int j = 1; j < 8; ++j) m = fmaxf(m, vj[j]);
#pragma unroll
    for (int off = 1; off < 8; off <<= 1) m = fmaxf(m, __shfl_xor(m, off));
    float s = 0.f;
#pragma unroll
    for (int j = 0; j < 8; ++j) s += expf(vj[j] - m);
#pragma unroll
    for (int off = 1; off < 8; off <<= 1) s += __shfl_xor(s, off);
    float ls = m + logf(s);
    if (lane < 5) {
        float4 o0, o1;
        o0.x = vj[0] - ls; o0.y = vj[1] - ls; o0.z = vj[2] - ls; o0.w = vj[3] - ls;
        o1.x = vj[4] - ls; o1.y = vj[5] - ls; o1.z = vj[6] - ls; o1.w = vj[7] - ls;
        float* op = out + (size_t)node * 40 + lane * 8;
        *reinterpret_cast<float4*>(op) = o0;
        *reinterpret_cast<float4*>(op + 4) = o1;
    }
}

// ---------------- launch ----------------

extern "C" void kernel_launch(void* const* d_in, const int* in_sizes, int n_in,
                              void* d_out, int out_size, void* d_ws, size_t ws_size,
                              hipStream_t stream) {
    const float* x    = (const float*)d_in[0];
    const int*   esrc = (const int*)d_in[1];
    const int*   edst = (const int*)d_in[2];
    const float* ew   = (const float*)d_in[3];

    const int nN = in_sizes[0] / 512;  // 100000
    const int nE = in_sizes[1];        // 3200000

    const int dims[10] = {512, 256, 256, 256, 256, 256, 128, 128, 64, 40};
    const int BUCKET_CAP = ((nE / 8) + (nE / 64) + 4095) & ~4095;  // ~12.5% headroom

    // ---- workspace layout (GEMM A-tile tail blocks read up to ~48KB past h; supp follows) ----
    char* ws = (char*)d_ws;
    unsigned short* h    = (unsigned short*)ws;                       // nN*256 bf16
    unsigned short* supp = (unsigned short*)(ws + (size_t)nN * 256 * 2);
    char* p = ws + (size_t)nN * 256 * 2 * 2;
    unsigned short* Wt = (unsigned short*)p; p += (1 << 21);
    int4* staging = (int4*)p; p += (size_t)8 * BUCKET_CAP * 16;
    int* deg      = (int*)p; p += ((size_t)nN + 64) * 4;
    int* rowptr   = (int*)p; p += ((size_t)nN + 64) * 4;
    int* cursor   = (int*)p; p += ((size_t)nN + 64) * 4;
    int* partials = (int*)p; p += 128 * 4;
    int* bucketCursor = (int*)p; p += 64 * 4;
    int2* ep      = (int2*)p; p += (size_t)nE * 8;

    // ---- prep: transpose+convert all weights, zero deg/bucketCursor ----
    TW tw;
    size_t woff[9];
    {
        int off = 0;
        for (int i = 0; i < 9; ++i) {
            tw.W[i] = (const float*)d_in[4 + 2 * i];
            tw.K[i] = dims[i];
            tw.N[i] = dims[i + 1];
            tw.base[i] = off;
            woff[i] = (size_t)off;
            int fop = cdiv(dims[i + 1], 64) * 64;
            off += fop * dims[i];
        }
        tw.base[9] = off;
        tw.nN = nN;
        int total = off;
        int nPrep = cdiv((total > nN + 8) ? total : nN + 8, 256);
        prep_kernel<<<nPrep, 256, 0, stream>>>(tw, Wt, deg, bucketCursor, total);
    }
    const float* b[9];
    for (int i = 0; i < 9; ++i) b[i] = (const float*)d_in[5 + 2 * i];

    // ---- CSR build: partition (count+bucket) -> scan -> per-bucket scatter ----
    partition_kernel<<<cdiv(nE, 256), 256, 0, stream>>>(esrc, edst, ew, deg, bucketCursor,
                                                        staging, BUCKET_CAP, nE, nN);
    {
        int nb = cdiv(nN, 1024);
        scan_part<<<nb, 256, 0, stream>>>(deg, partials, nN);
        scan_mid<<<1, 128, 0, stream>>>(partials, rowptr, nb, nN);
        scan_final<<<nb, 256, 0, stream>>>(deg, partials, rowptr, cursor, nN);
    }
    scatter_b<<<8 * 256, 256, 0, stream>>>(staging, bucketCursor, BUCKET_CAP, cursor, ep, 256);

    const int aggBlocks = cdiv(nN, 4);  // 4 waves/block, 1 node/wave

    const void* A = (const void*)x;
    for (int L = 0; L < 9; ++L) {
        int fi = dims[L], fo = dims[L + 1];
        if (L == 8) {
            dim3 g(cdiv(nN, 128), 1);
            gemm_mfma<64, false><<<g, 256, 0, stream>>>(A, Wt + woff[L], supp, nN, fi, 64);
            agg_lsm_kernel<<<aggBlocks, 256, 0, stream>>>(supp, ep, rowptr, b[8], (float*)d_out, nN);
            break;
        }
        int BN = (fo >= 128) ? 128 : 64;
        dim3 g(cdiv(nN, 128), cdiv(fo, BN));
        if (L == 0)
            gemm_mfma<128, true><<<g, 256, 0, stream>>>(A, Wt + woff[L], supp, nN, fi, fo);
        else if (BN == 128)
            gemm_mfma<128, false><<<g, 256, 0, stream>>>(A, Wt + woff[L], supp, nN, fi, fo);
        else
            gemm_mfma<64, false><<<g, 256, 0, stream>>>(A, Wt + woff[L], supp, nN, fi, fo);
        if (fo == 256)
            agg_kernel<256><<<aggBlocks, 256, 0, stream>>>(supp, ep, rowptr, b[L], h, nN);
        else if (fo == 128)
            agg_kernel<128><<<aggBlocks, 256, 0, stream>>>(supp, ep, rowptr, b[L], h, nN);
        else
            agg_kernel<64><<<aggBlocks, 256, 0, stream>>>(supp, ep, rowptr, b[L], h, nN);
        A = (const void*)h;
    }
}